// Round 3
// baseline (255.539 us; speedup 1.0000x reference)
//
#include <hip/hip_runtime.h>

#define N_ROWS 8192
#define DIM    512

typedef __attribute__((ext_vector_type(8))) short frag_ab;  // 8 bf16 (4 VGPRs)
typedef __attribute__((ext_vector_type(4))) float frag_cd;  // 4 fp32 acc

__device__ __forceinline__ unsigned short f2bf(float f) {
    unsigned u = __float_as_uint(f);
    u += 0x7FFFu + ((u >> 16) & 1u);   // RNE
    return (unsigned short)(u >> 16);
}
__device__ __forceinline__ unsigned pack2(float a, float b) {
    return (unsigned)f2bf(a) | ((unsigned)f2bf(b) << 16);
}
// order-preserving f32 -> u32 key (monotone), so atomicMax(uint) == float max
__device__ __forceinline__ unsigned enc_f32(float f) {
    unsigned u = __float_as_uint(f);
    return (u & 0x80000000u) ? ~u : (u | 0x80000000u);
}
__device__ __forceinline__ float dec_f32(unsigned k) {
    return __uint_as_float((k & 0x80000000u) ? (k & 0x7FFFFFFFu) : ~k);
}

// ---- kernel 1: fused fp32->bf16 convert + fp32 diag dot + max-key init ----
// One wave per row; reads imgs+caps exactly once (64 MB), writes bf16 (32 MB).
__global__ __launch_bounds__(256) void k_prep(const float* __restrict__ imgs,
                                              const float* __restrict__ caps,
                                              uint4* __restrict__ bimgs,
                                              uint4* __restrict__ bcaps,
                                              float* __restrict__ diag,
                                              unsigned* __restrict__ rowmax,
                                              unsigned* __restrict__ colmax) {
    const int w = threadIdx.x >> 6, lane = threadIdx.x & 63;
    const int row = blockIdx.x * 4 + w;
    const float4* ip = (const float4*)(imgs + (size_t)row * DIM);
    const float4* cp = (const float4*)(caps + (size_t)row * DIM);
    float4 a0 = ip[2 * lane], a1 = ip[2 * lane + 1];
    float4 b0 = cp[2 * lane], b1 = cp[2 * lane + 1];
    uint4 oa, ob;
    oa.x = pack2(a0.x, a0.y); oa.y = pack2(a0.z, a0.w);
    oa.z = pack2(a1.x, a1.y); oa.w = pack2(a1.z, a1.w);
    ob.x = pack2(b0.x, b0.y); ob.y = pack2(b0.z, b0.w);
    ob.z = pack2(b1.x, b1.y); ob.w = pack2(b1.z, b1.w);
    bimgs[row * 64 + lane] = oa;
    bcaps[row * 64 + lane] = ob;
    float s = a0.x * b0.x + a0.y * b0.y + a0.z * b0.z + a0.w * b0.w
            + a1.x * b1.x + a1.y * b1.y + a1.z * b1.z + a1.w * b1.w;
    #pragma unroll
    for (int m = 1; m < 64; m <<= 1) s += __shfl_xor(s, m, 64);
    if (lane == 0) { diag[row] = s; rowmax[row] = 0u; colmax[row] = 0u; }
}

// ---- kernel 2: fused bf16 NT-GEMM + diag flip + row/col max ----
// Round-1 structure (BK=32, 2-barrier K-loop), single change: staging map is
// column-group-major within each 16-row x 32-col chunk:
//   lane -> (rowin = lane&15, cg = lane>>4)
// LDS slot(row,cg) = cg*16 + row  => fragment read (row=l15, q) hits bank
// group (l15*4)%32 -> 2 lanes/bank-group = conflict-free (2-way is free).
// Global lines per glds unchanged: 16 fully-consumed 64B lines.
__global__ __launch_bounds__(256) void k_gemm(const unsigned short* __restrict__ A,
                                              const unsigned short* __restrict__ B,
                                              unsigned* __restrict__ rowmax,
                                              unsigned* __restrict__ colmax) {
    __shared__ unsigned short sA[128 * 32];   // 8 KB: 8 chunks of (16 rows x 32 cols)
    __shared__ unsigned short sB[128 * 32];
    const int tid = threadIdx.x;
    const int w = tid >> 6, lane = tid & 63;
    const int i0 = (int)blockIdx.y << 7, j0 = (int)blockIdx.x << 7;
    const int q = lane >> 4, l15 = lane & 15;
    const int wrow = (w >> 1) << 6, wcol = (w & 1) << 6;

    frag_cd acc[4][4] = {};

    const int srow = lane & 15;            // row within 16-row chunk
    const int scol = (lane >> 4) << 3;     // col group 0,8,16,24 elems

    for (int k0 = 0; k0 < DIM; k0 += 32) {
        __syncthreads();  // prior ds_reads retired before LDS overwrite
        #pragma unroll
        for (int j = 0; j < 2; ++j) {
            int r = ((j * 4 + w) << 4) + srow;  // tile row 0..127
            const unsigned short* gA = A + (size_t)(i0 + r) * DIM + k0 + scol;
            const unsigned short* gB = B + (size_t)(j0 + r) * DIM + k0 + scol;
            // LDS dest = wave-uniform base + lane*16B (required layout)
            unsigned short* lA = sA + ((j * 4 + w) << 9) + (lane << 3);
            unsigned short* lB = sB + ((j * 4 + w) << 9) + (lane << 3);
            __builtin_amdgcn_global_load_lds(
                (const __attribute__((address_space(1))) unsigned int*)gA,
                (__attribute__((address_space(3))) unsigned int*)lA, 16, 0, 0);
            __builtin_amdgcn_global_load_lds(
                (const __attribute__((address_space(1))) unsigned int*)gB,
                (__attribute__((address_space(3))) unsigned int*)lB, 16, 0, 0);
        }
        __syncthreads();  // drains vmcnt -> LDS valid

        frag_ab af[4], bfr[4];
        #pragma unroll
        for (int r = 0; r < 4; ++r)   // chunk = (w>>1)*4 + r, slot = q*16 + l15
            af[r] = *(const frag_ab*)(sA + ((((w >> 1) << 2) + r) << 9) + (q << 7) + (l15 << 3));
        #pragma unroll
        for (int c = 0; c < 4; ++c)
            bfr[c] = *(const frag_ab*)(sB + ((((w & 1) << 2) + c) << 9) + (q << 7) + (l15 << 3));
        #pragma unroll
        for (int r = 0; r < 4; ++r)
            #pragma unroll
            for (int c = 0; c < 4; ++c)
                acc[r][c] = __builtin_amdgcn_mfma_f32_16x16x32_bf16(af[r], bfr[c], acc[r][c], 0, 0, 0);
    }

    // ---- epilogue: diagonal flip + row/col max + device atomics ----
    // C/D layout: col = lane&15, row = (lane>>4)*4 + reg  [m89-verified]
    const bool dblk = (i0 == j0);
    #pragma unroll
    for (int r = 0; r < 4; ++r)
        #pragma unroll
        for (int c = 0; c < 4; ++c)
            #pragma unroll
            for (int g = 0; g < 4; ++g) {
                float f = acc[r][c][g];
                if (dblk && (wrow + (r << 4) + (q << 2) + g) == (wcol + (c << 4) + l15))
                    f = -f;   // s[i][i] = -diag
                acc[r][c][g] = f;
            }

    // row maxes: reduce over c (in-reg) then over lane&15 (xor 1,2,4,8)
    #pragma unroll
    for (int r = 0; r < 4; ++r)
        #pragma unroll
        for (int g = 0; g < 4; ++g) {
            float m = fmaxf(fmaxf(acc[r][0][g], acc[r][1][g]),
                            fmaxf(acc[r][2][g], acc[r][3][g]));
            m = fmaxf(m, __shfl_xor(m, 1, 64));
            m = fmaxf(m, __shfl_xor(m, 2, 64));
            m = fmaxf(m, __shfl_xor(m, 4, 64));
            m = fmaxf(m, __shfl_xor(m, 8, 64));
            if (l15 == 0)
                atomicMax(&rowmax[i0 + wrow + (r << 4) + (q << 2) + g], enc_f32(m));
        }
    // col maxes: reduce over r,g (in-reg) then over q (xor 16,32)
    #pragma unroll
    for (int c = 0; c < 4; ++c) {
        float m = acc[0][c][0];
        #pragma unroll
        for (int r = 0; r < 4; ++r)
            #pragma unroll
            for (int g = 0; g < 4; ++g) m = fmaxf(m, acc[r][c][g]);
        m = fmaxf(m, __shfl_xor(m, 16, 64));
        m = fmaxf(m, __shfl_xor(m, 32, 64));
        if (q == 0)
            atomicMax(&colmax[j0 + wcol + (c << 4) + l15], enc_f32(m));
    }
}

// ---- kernel 3: hinge terms + scalar reduce ----
__global__ __launch_bounds__(256) void k_final(const unsigned* __restrict__ rowmax,
                                               const unsigned* __restrict__ colmax,
                                               const float* __restrict__ diag,
                                               float* __restrict__ out) {
    int tid = threadIdx.x;
    float s = 0.f;
    for (int i = tid; i < N_ROWS; i += 256) {
        float d = diag[i];
        s += fmaxf(dec_f32(rowmax[i]) + 0.2f - d, 0.f);  // neg_img
        s += fmaxf(dec_f32(colmax[i]) + 0.2f - d, 0.f);  // neg_cap
    }
    #pragma unroll
    for (int m = 1; m < 64; m <<= 1) s += __shfl_xor(s, m, 64);
    __shared__ float red[4];
    if ((tid & 63) == 0) red[tid >> 6] = s;
    __syncthreads();
    if (tid == 0) out[0] = red[0] + red[1] + red[2] + red[3];
}

extern "C" void kernel_launch(void* const* d_in, const int* in_sizes, int n_in,
                              void* d_out, int out_size, void* d_ws, size_t ws_size,
                              hipStream_t stream) {
    const float* imgs = (const float*)d_in[0];
    const float* caps = (const float*)d_in[1];
    float* out = (float*)d_out;

    char* ws = (char*)d_ws;
    unsigned short* bimgs = (unsigned short*)ws;                       // 8 MB
    unsigned short* bcaps = (unsigned short*)(ws + 8388608);           // 8 MB
    float*    diag   = (float*)   (ws + 16777216);                     // 32 KB
    unsigned* rowmax = (unsigned*)(ws + 16777216 + 32768);             // 32 KB
    unsigned* colmax = (unsigned*)(ws + 16777216 + 65536);             // 32 KB

    k_prep<<<N_ROWS / 4, 256, 0, stream>>>(imgs, caps, (uint4*)bimgs, (uint4*)bcaps,
                                           diag, rowmax, colmax);
    k_gemm<<<dim3(64, 64), 256, 0, stream>>>(bimgs, bcaps, rowmax, colmax);
    k_final<<<1, 256, 0, stream>>>(rowmax, colmax, diag, out);
}

// Round 4
// 191.320 us; speedup vs baseline: 1.3357x; 1.3357x over previous
//
#include <hip/hip_runtime.h>

#define N_ROWS 8192
#define DIM    512

typedef __attribute__((ext_vector_type(8))) short frag_ab;  // 8 bf16 (4 VGPRs)
typedef __attribute__((ext_vector_type(4))) float frag_cd;  // 4 fp32 acc

__device__ __forceinline__ unsigned short f2bf(float f) {
    unsigned u = __float_as_uint(f);
    u += 0x7FFFu + ((u >> 16) & 1u);   // RNE
    return (unsigned short)(u >> 16);
}
__device__ __forceinline__ unsigned pack2(float a, float b) {
    return (unsigned)f2bf(a) | ((unsigned)f2bf(b) << 16);
}
// order-preserving f32 -> u32 key (monotone), so atomicMax(uint) == float max
__device__ __forceinline__ unsigned enc_f32(float f) {
    unsigned u = __float_as_uint(f);
    return (u & 0x80000000u) ? ~u : (u | 0x80000000u);
}
__device__ __forceinline__ float dec_f32(unsigned k) {
    return __uint_as_float((k & 0x80000000u) ? (k & 0x7FFFFFFFu) : ~k);
}

// ---- TILED bf16 layout ----
// 16B-unit index = cr*1024 + cc*64 + cg*16 + rin
//   cr = row>>4, rin = row&15, cc = col>>5, cg = (col>>3)&3  (8 elems per unit)
// One chunk (cr,cc) = 64 units = 1KB contiguous. k_gemm stages a chunk with ONE
// glds instruction: lane L reads unit L (monotone, perfectly coalesced) into
// LDS slot L. Fragment reads (addr16 = q*16+l15) are conflict-free (round-3 HW
// verified: 0 bank conflicts).

// ---- kernel 1: fused convert-to-tiled + fp32 diag + max-key init ----
// One block per 16-row chunk-row; reads both matrices' chunk-rows (64KB fp32),
// writes tiled bf16 (2x16KB, lane-contiguous 4KB per store instr), diag for 16 rows.
__global__ __launch_bounds__(256) void k_prep(const float* __restrict__ imgs,
                                              const float* __restrict__ caps,
                                              uint4* __restrict__ bimgs,
                                              uint4* __restrict__ bcaps,
                                              float* __restrict__ diag,
                                              unsigned* __restrict__ rowmax,
                                              unsigned* __restrict__ colmax) {
    const int cr = blockIdx.x;            // 0..511
    const int t  = threadIdx.x;           // 0..255
    const int rin = t & 15;
    const int cg  = (t >> 4) & 3;
    const int row = cr * 16 + rin;
    float dsum = 0.f;
    #pragma unroll
    for (int i = 0; i < 4; ++i) {
        const int cc = i * 4 + (t >> 6);
        const int colbase = cc * 32 + cg * 8;
        const float4* ip = (const float4*)(imgs + (size_t)row * DIM + colbase);
        const float4* cp = (const float4*)(caps + (size_t)row * DIM + colbase);
        float4 a0 = ip[0], a1 = ip[1];
        float4 b0 = cp[0], b1 = cp[1];
        uint4 oa, ob;
        oa.x = pack2(a0.x, a0.y); oa.y = pack2(a0.z, a0.w);
        oa.z = pack2(a1.x, a1.y); oa.w = pack2(a1.z, a1.w);
        ob.x = pack2(b0.x, b0.y); ob.y = pack2(b0.z, b0.w);
        ob.z = pack2(b1.x, b1.y); ob.w = pack2(b1.z, b1.w);
        const int u = i * 256 + t;        // == cc*64 + cg*16 + rin  (contiguous store)
        bimgs[(size_t)cr * 1024 + u] = oa;
        bcaps[(size_t)cr * 1024 + u] = ob;
        dsum += a0.x * b0.x + a0.y * b0.y + a0.z * b0.z + a0.w * b0.w
              + a1.x * b1.x + a1.y * b1.y + a1.z * b1.z + a1.w * b1.w;
    }
    __shared__ float sred[256];
    sred[t] = dsum;
    __syncthreads();
    if (t < 16) {
        float s = 0.f;
        #pragma unroll
        for (int k = 0; k < 16; ++k) s += sred[t + 16 * k];
        const int r = cr * 16 + t;
        diag[r] = s; rowmax[r] = 0u; colmax[r] = 0u;
    }
}

// ---- kernel 2: fused bf16 NT-GEMM + diag flip + row/col max ----
// Round-3 structure and reader verbatim (0 LDS conflicts, HW-verified); only
// the glds SOURCE changes: tiled layout -> lane-monotone 1KB contiguous runs.
__global__ __launch_bounds__(256) void k_gemm(const uint4* __restrict__ A,
                                              const uint4* __restrict__ B,
                                              unsigned* __restrict__ rowmax,
                                              unsigned* __restrict__ colmax) {
    __shared__ unsigned short sA[128 * 32];   // 8 KB: 8 chunk slots of 1KB
    __shared__ unsigned short sB[128 * 32];
    const int tid = threadIdx.x;
    const int w = tid >> 6, lane = tid & 63;
    const int i0 = (int)blockIdx.y << 7, j0 = (int)blockIdx.x << 7;
    const int q = lane >> 4, l15 = lane & 15;
    const int wrow = (w >> 1) << 6, wcol = (w & 1) << 6;

    frag_cd acc[4][4] = {};

    for (int k0 = 0; k0 < DIM; k0 += 32) {
        const int cc64 = (k0 >> 5) << 6;               // chunk_c * 64 units
        __syncthreads();  // prior ds_reads retired before LDS overwrite
        #pragma unroll
        for (int j = 0; j < 2; ++j) {
            const int s = j * 4 + w;                   // chunk slot 0..7
            const uint4* gA = A + (size_t)((i0 >> 4) + s) * 1024 + cc64 + lane;
            const uint4* gB = B + (size_t)((j0 >> 4) + s) * 1024 + cc64 + lane;
            unsigned short* lA = sA + (s << 9) + (lane << 3);
            unsigned short* lB = sB + (s << 9) + (lane << 3);
            __builtin_amdgcn_global_load_lds(
                (const __attribute__((address_space(1))) unsigned int*)gA,
                (__attribute__((address_space(3))) unsigned int*)lA, 16, 0, 0);
            __builtin_amdgcn_global_load_lds(
                (const __attribute__((address_space(1))) unsigned int*)gB,
                (__attribute__((address_space(3))) unsigned int*)lB, 16, 0, 0);
        }
        __syncthreads();  // drains vmcnt -> LDS valid

        frag_ab af[4], bfr[4];
        #pragma unroll
        for (int r = 0; r < 4; ++r)   // slot = (w>>1)*4+r, unit = q*16+l15
            af[r] = *(const frag_ab*)(sA + ((((w >> 1) << 2) + r) << 9) + (q << 7) + (l15 << 3));
        #pragma unroll
        for (int c = 0; c < 4; ++c)
            bfr[c] = *(const frag_ab*)(sB + ((((w & 1) << 2) + c) << 9) + (q << 7) + (l15 << 3));
        #pragma unroll
        for (int r = 0; r < 4; ++r)
            #pragma unroll
            for (int c = 0; c < 4; ++c)
                acc[r][c] = __builtin_amdgcn_mfma_f32_16x16x32_bf16(af[r], bfr[c], acc[r][c], 0, 0, 0);
    }

    // ---- epilogue: diagonal flip + row/col max + device atomics ----
    // C/D layout: col = lane&15, row = (lane>>4)*4 + reg  [m89-verified]
    const bool dblk = (i0 == j0);
    #pragma unroll
    for (int r = 0; r < 4; ++r)
        #pragma unroll
        for (int c = 0; c < 4; ++c)
            #pragma unroll
            for (int g = 0; g < 4; ++g) {
                float f = acc[r][c][g];
                if (dblk && (wrow + (r << 4) + (q << 2) + g) == (wcol + (c << 4) + l15))
                    f = -f;   // s[i][i] = -diag
                acc[r][c][g] = f;
            }

    // row maxes: reduce over c (in-reg) then over lane&15 (xor 1,2,4,8)
    #pragma unroll
    for (int r = 0; r < 4; ++r)
        #pragma unroll
        for (int g = 0; g < 4; ++g) {
            float m = fmaxf(fmaxf(acc[r][0][g], acc[r][1][g]),
                            fmaxf(acc[r][2][g], acc[r][3][g]));
            m = fmaxf(m, __shfl_xor(m, 1, 64));
            m = fmaxf(m, __shfl_xor(m, 2, 64));
            m = fmaxf(m, __shfl_xor(m, 4, 64));
            m = fmaxf(m, __shfl_xor(m, 8, 64));
            if (l15 == 0)
                atomicMax(&rowmax[i0 + wrow + (r << 4) + (q << 2) + g], enc_f32(m));
        }
    // col maxes: reduce over r,g (in-reg) then over q (xor 16,32)
    #pragma unroll
    for (int c = 0; c < 4; ++c) {
        float m = acc[0][c][0];
        #pragma unroll
        for (int r = 0; r < 4; ++r)
            #pragma unroll
            for (int g = 0; g < 4; ++g) m = fmaxf(m, acc[r][c][g]);
        m = fmaxf(m, __shfl_xor(m, 16, 64));
        m = fmaxf(m, __shfl_xor(m, 32, 64));
        if (q == 0)
            atomicMax(&colmax[j0 + wcol + (c << 4) + l15], enc_f32(m));
    }
}

// ---- kernel 3: hinge terms + scalar reduce ----
__global__ __launch_bounds__(256) void k_final(const unsigned* __restrict__ rowmax,
                                               const unsigned* __restrict__ colmax,
                                               const float* __restrict__ diag,
                                               float* __restrict__ out) {
    int tid = threadIdx.x;
    float s = 0.f;
    for (int i = tid; i < N_ROWS; i += 256) {
        float d = diag[i];
        s += fmaxf(dec_f32(rowmax[i]) + 0.2f - d, 0.f);  // neg_img
        s += fmaxf(dec_f32(colmax[i]) + 0.2f - d, 0.f);  // neg_cap
    }
    #pragma unroll
    for (int m = 1; m < 64; m <<= 1) s += __shfl_xor(s, m, 64);
    __shared__ float red[4];
    if ((tid & 63) == 0) red[tid >> 6] = s;
    __syncthreads();
    if (tid == 0) out[0] = red[0] + red[1] + red[2] + red[3];
}

extern "C" void kernel_launch(void* const* d_in, const int* in_sizes, int n_in,
                              void* d_out, int out_size, void* d_ws, size_t ws_size,
                              hipStream_t stream) {
    const float* imgs = (const float*)d_in[0];
    const float* caps = (const float*)d_in[1];
    float* out = (float*)d_out;

    char* ws = (char*)d_ws;
    uint4* bimgs = (uint4*)ws;                                         // 8 MB tiled
    uint4* bcaps = (uint4*)(ws + 8388608);                             // 8 MB tiled
    float*    diag   = (float*)   (ws + 16777216);                     // 32 KB
    unsigned* rowmax = (unsigned*)(ws + 16777216 + 32768);             // 32 KB
    unsigned* colmax = (unsigned*)(ws + 16777216 + 65536);             // 32 KB

    k_prep<<<N_ROWS / 16, 256, 0, stream>>>(imgs, caps, bimgs, bcaps,
                                            diag, rowmax, colmax);
    k_gemm<<<dim3(64, 64), 256, 0, stream>>>(bimgs, bcaps, rowmax, colmax);
    k_final<<<1, 256, 0, stream>>>(rowmax, colmax, diag, out);
}